// Round 7
// baseline (175.832 us; speedup 1.0000x reference)
//
#include <hip/hip_runtime.h>
#include <hip/hip_bf16.h>

typedef unsigned long long u64;
typedef unsigned int u32;

#define A_TOTAL 76725
#define A_PAD   76736            /* padded to /4 for float4 loads */
#define QCH     (A_PAD / 4)
#define NCLS 90
#define KTOP 5000u
#define MAXT 100
#define KTHR 0x3D4CCCCDu         /* bits of 0.05f */
#define NTH  256                 /* nms threads */

__device__ __forceinline__ u64 pack_key(u32 k, u32 i) {
  return ((u64)k << 32) | (u64)(0xFFFFFFFFu - i);
}

// Cutoff scan (wave 0). Smallest bucket B with sum(b>=B) >= need.
__device__ __forceinline__ u32 scan_cut(const u32* gh, u32 need, int tid) {
  int base = 4095 - tid * 64;
  u32 s = 0;
  #pragma unroll
  for (int j = 0; j < 64; ++j) s += gh[base - j];
  u32 incl = s;
  #pragma unroll
  for (int off = 1; off < 64; off <<= 1) {
    u32 o = __shfl_up(incl, off, 64);
    if (tid >= off) incl += o;
  }
  u32 excl = incl - s;
  bool cross = (excl < need) && (incl >= need);
  u64 bal = __ballot(cross);
  int cl = __ffsll((unsigned long long)bal) - 1;
  int cbase = 4095 - cl * 64;
  u32 cexcl = __shfl(excl, cl, 64);
  u32 v = gh[cbase - tid];
  u32 incl2 = v;
  #pragma unroll
  for (int off = 1; off < 64; off <<= 1) {
    u32 o = __shfl_up(incl2, off, 64);
    if (tid >= off) incl2 += o;
  }
  bool c2 = (cexcl + incl2 >= need) && (cexcl + incl2 - v < need);
  u64 bal2 = __ballot(c2);
  int j2 = __ffsll((unsigned long long)bal2) - 1;
  return (u32)(cbase - j2);
}

// Full wave-0 cut with totals.
__device__ __forceinline__ void cut4096w(const u32* hh, u32 need, int wl,
                                         u32& B, u32& incl, u32& above, u32& total) {
  int lo = wl << 6;
  u32 s = 0;
  #pragma unroll
  for (int j = 0; j < 64; ++j) s += hh[lo + j];
  u32 suf = s;
  #pragma unroll
  for (int off = 1; off < 64; off <<= 1) {
    u32 v = __shfl_down(suf, off, 64);
    if (wl < 64 - off) suf += v;
  }
  total = __shfl(suf, 0, 64);
  if (total < need) { B = 0; incl = total; above = 0; return; }
  u32 sufnext = suf - s;
  bool cross = (suf >= need) && (sufnext < need);
  u64 bal = __ballot(cross);
  int gl = (int)__ffsll((unsigned long long)bal) - 1;
  int glo = gl << 6;
  u32 aboveG = __shfl(sufnext, gl, 64);
  u32 hb = hh[glo + wl];
  u32 sufb = hb;
  #pragma unroll
  for (int off = 1; off < 64; off <<= 1) {
    u32 v = __shfl_down(sufb, off, 64);
    if (wl < 64 - off) sufb += v;
  }
  bool c2 = (aboveG + sufb >= need) && (aboveG + sufb - hb < need);
  u64 bal2 = __ballot(c2);
  int jB = (int)__ffsll((unsigned long long)bal2) - 1;
  B = (u32)(glo + jB);
  incl = aboveG + __shfl(sufb, jB, 64);
  above = incl - __shfl(hb, jB, 64);
}

// Block-cooperative descending bitonic sort of a[0..n) padded to pow2 with 0.
__device__ __forceinline__ void bitonic_desc(u64* a, u32 n, int tid, int nth) {
  u32 P = 2; while (P < n) P <<= 1;
  for (u32 i = tid; i < P; i += nth) if (i >= n) a[i] = 0ULL;
  __syncthreads();
  for (u32 kk = 2; kk <= P; kk <<= 1) {
    for (u32 jj = kk >> 1; jj; jj >>= 1) {
      for (u32 i = tid; i < P; i += nth) {
        u32 ixj = i ^ jj;
        if (ixj > i) {
          u64 x = a[i], y = a[ixj];
          bool up = ((i & kk) == 0);
          if (up ? (x < y) : (x > y)) { a[i] = y; a[ixj] = x; }
        }
      }
      __syncthreads();
    }
  }
}

// Wave-level lazy greedy NMS scan over sorted candidates (one wave, no barriers).
// Returns updated winner count. All 64 lanes of wave 0 must call.
__device__ __forceinline__ int lazy_scan(const u64* key_s, const float4* box_s, u32 C,
                                         float4* wbox, float* outS, float* outB,
                                         int w, int wl) {
  u32 cur = 0;
  while (w < MAXT && cur < C) {
    u32 p = cur + (u32)wl;
    bool aliveL = (p < C);
    u64 kk = aliveL ? key_s[p] : 0ull;
    float4 mybox;
    if (aliveL) mybox = box_s[p];
    float myarea = aliveL ? (mybox.z - mybox.x) * (mybox.w - mybox.y) : 0.f;
    for (int j = 0; j < w; ++j) {
      if (aliveL) {
        float4 pb = wbox[j];
        float yy1 = fmaxf(pb.x, mybox.x), xx1 = fmaxf(pb.y, mybox.y);
        float yy2 = fminf(pb.z, mybox.z), xx2 = fminf(pb.w, mybox.w);
        float inter = fmaxf(yy2 - yy1, 0.0f) * fmaxf(xx2 - xx1, 0.0f);
        float pa = (pb.z - pb.x) * (pb.w - pb.y);
        if (inter / (pa + myarea - inter + 1e-8f) > 0.3f) aliveL = false;
      }
    }
    for (;;) {
      u64 bal = __ballot(aliveL);
      if (bal == 0ull) break;
      int js = (int)__ffsll((unsigned long long)bal) - 1;
      float4 pb;
      pb.x = __shfl(mybox.x, js, 64);
      pb.y = __shfl(mybox.y, js, 64);
      pb.z = __shfl(mybox.z, js, 64);
      pb.w = __shfl(mybox.w, js, 64);
      u64 wk = __shfl(kk, js, 64);
      if (wl == 0) {
        outS[w] = __uint_as_float((u32)(wk >> 32));
        *(float4*)(outB + w * 4) = pb;
        wbox[w] = pb;
      }
      w++;
      if (w >= MAXT) break;
      if (wl <= js) aliveL = false;
      else if (aliveL) {
        float yy1 = fmaxf(pb.x, mybox.x), xx1 = fmaxf(pb.y, mybox.y);
        float yy2 = fminf(pb.z, mybox.z), xx2 = fminf(pb.w, mybox.w);
        float inter = fmaxf(yy2 - yy1, 0.0f) * fmaxf(xx2 - xx1, 0.0f);
        float pa = (pb.z - pb.x) * (pb.w - pb.y);
        if (inter / (pa + myarea - inter + 1e-8f) > 0.3f) aliveL = false;
      }
    }
    cur += 64;
  }
  return w;
}

// ---------------- decode + clip (+ zero hist/counters/pad) ----------------
__global__ __launch_bounds__(256) void decode_kernel(
    const float* __restrict__ bx0, const float* __restrict__ bx1, const float* __restrict__ bx2,
    const float* __restrict__ bx3, const float* __restrict__ bx4,
    const float* __restrict__ an0, const float* __restrict__ an1, const float* __restrict__ an2,
    const float* __restrict__ an3, const float* __restrict__ an4,
    const float* __restrict__ img, float* __restrict__ boxes,
    u32* __restrict__ zero_base, float* __restrict__ scores_t)
{
  int t = blockIdx.x * blockDim.x + threadIdx.x;
  int nth = gridDim.x * blockDim.x;
  for (int i = t; i < 180 * 4096 + 900; i += nth) zero_base[i] = 0;
  if (t < 180 * (A_PAD - A_TOTAL)) {
    int lane = t / (A_PAD - A_TOTAL), off = t % (A_PAD - A_TOTAL);
    scores_t[(size_t)lane * A_PAD + A_TOTAL + off] = 0.0f;
  }
  if (t >= 2 * A_TOTAL) return;
  int b = t / A_TOTAL, a = t % A_TOTAL;
  const float* bp; const float* ap; int al; int nl;
  if (a < 57600)      { bp = bx0; ap = an0; al = a;          nl = 57600; }
  else if (a < 72000) { bp = bx1; ap = an1; al = a - 57600;  nl = 14400; }
  else if (a < 75600) { bp = bx2; ap = an2; al = a - 72000;  nl = 3600;  }
  else if (a < 76500) { bp = bx3; ap = an3; al = a - 75600;  nl = 900;   }
  else                { bp = bx4; ap = an4; al = a - 76500;  nl = 225;   }
  float4 e  = *(const float4*)(bp + ((size_t)b * nl + al) * 4);
  float4 an = *(const float4*)(ap + ((size_t)b * nl + al) * 4);
  const float CLIP = 4.135166556742356f; // log(1000/16)
  float ah  = an.z - an.x + 1.0f;
  float aw  = an.w - an.y + 1.0f;
  float ayc = an.x + 0.5f * ah;
  float axc = an.y + 0.5f * aw;
  float dh = fminf(e.z, CLIP), dw = fminf(e.w, CLIP);
  float yc = e.x * ah + ayc;
  float xc = e.y * aw + axc;
  float h  = expf(dh) * ah;
  float w  = expf(dw) * aw;
  float ymin = yc - 0.5f * h;
  float xmin = xc - 0.5f * w;
  float ymax = ymin + h - 1.0f;
  float xmax = xmin + w - 1.0f;
  float H = img[b * 2 + 0], W = img[b * 2 + 1];
  float4 o;
  o.x = fminf(fmaxf(ymin, 0.0f), H);
  o.y = fminf(fmaxf(xmin, 0.0f), W);
  o.z = fminf(fmaxf(ymax, 0.0f), H);
  o.w = fminf(fmaxf(xmax, 0.0f), W);
  *(float4*)(boxes + (size_t)t * 4) = o;
}

// ---------------- sigmoid + transpose to [B,90,A_PAD] ----------------
__global__ __launch_bounds__(256) void transpose_kernel(
    const float* __restrict__ c3, const float* __restrict__ c4, const float* __restrict__ c5,
    const float* __restrict__ c6, const float* __restrict__ c7, float* __restrict__ scores_t)
{
  __shared__ float lds[64 * 91];
  int blk = blockIdx.x;
  int lvl, local;
  if      (blk < 1800) { lvl = 0; local = blk; }
  else if (blk < 2250) { lvl = 1; local = blk - 1800; }
  else if (blk < 2364) { lvl = 2; local = blk - 2250; }
  else if (blk < 2394) { lvl = 3; local = blk - 2364; }
  else                 { lvl = 4; local = blk - 2394; }
  const int ns[5]    = {57600, 14400, 3600, 900, 225};
  const int bases[5] = {0, 57600, 72000, 75600, 76500};
  const int tl[5]    = {900, 225, 57, 15, 4};
  const float* cls = (lvl == 0) ? c3 : (lvl == 1) ? c4 : (lvl == 2) ? c5 : (lvl == 3) ? c6 : c7;
  int n = ns[lvl], base = bases[lvl], tiles = tl[lvl];
  int b = local / tiles, tile = local % tiles;
  int a0 = tile * 64;
  int cnt = n - a0; if (cnt > 64) cnt = 64;
  const float* src = cls + ((size_t)b * n + a0) * 91;
  int total = cnt * 91;
  for (int i = threadIdx.x; i < total; i += 256) lds[i] = src[i];
  __syncthreads();
  for (int j = threadIdx.x; j < NCLS * 64; j += 256) {
    int c = j >> 6, a = j & 63;
    if (a < cnt) {
      float x = lds[a * 91 + c + 1];
      scores_t[((size_t)(b * NCLS + c)) * A_PAD + base + a0 + a] = 1.0f / (1.0f + expf(-x));
    }
  }
}

// ---------------- per-lane global histograms (2x replicated vs atomic contention) ----------------
__global__ __launch_bounds__(512) void hist_kernel(const float* __restrict__ scores_t,
                                                   u32* __restrict__ hist_g)
{
  __shared__ u32 hist[8192];
  int tid = threadIdx.x;
  int lane = blockIdx.x >> 2, q = blockIdx.x & 3;
  for (int i = tid; i < 8192; i += 512) hist[i] = 0;
  __syncthreads();
  u32 par = (u32)(tid & 1);
  const float4* S4 = (const float4*)(scores_t + (size_t)lane * A_PAD + q * QCH);
  for (int i = tid; i < QCH / 4; i += 512) {
    float4 v = S4[i];
    atomicAdd(&hist[((__float_as_uint(v.x) >> 19) << 1) | par], 1u);
    atomicAdd(&hist[((__float_as_uint(v.y) >> 19) << 1) | par], 1u);
    atomicAdd(&hist[((__float_as_uint(v.z) >> 19) << 1) | par], 1u);
    atomicAdd(&hist[((__float_as_uint(v.w) >> 19) << 1) | par], 1u);
  }
  __syncthreads();
  u32* gh = hist_g + (size_t)lane * 4096;
  for (int i = tid; i < 4096; i += 512) {
    u32 v = hist[2 * i] + hist[2 * i + 1];
    if (v) atomicAdd(&gh[i], v);
  }
}

// ---------------- collect candidates into per-lane global lists (+ top-1k listT) ----------------
__global__ __launch_bounds__(512) void collect_kernel(
    const float* __restrict__ scores_t, const u32* __restrict__ hist_g,
    u64* __restrict__ listA_g, u64* __restrict__ listE_g, u64* __restrict__ listT_g,
    u32* __restrict__ cntA_g, u32* __restrict__ cntE_g, u32* __restrict__ cntT_g,
    u32* __restrict__ B_g, u32* __restrict__ B1k_g)
{
  __shared__ u64 bufA[5120];
  __shared__ u64 bufE[2048];
  __shared__ u64 bufT[2048];
  __shared__ u32 sh_B, sh_B1k, sh_cA, sh_cE, sh_cT, sh_baseA, sh_baseE, sh_baseT;
  int tid = threadIdx.x;
  int lane = blockIdx.x >> 2, q = blockIdx.x & 3;
  const u32* gh = hist_g + (size_t)lane * 4096;
  if (tid < 64) {
    u32 B = scan_cut(gh, KTOP, tid);
    u32 B1k = scan_cut(gh, 1024u, tid);
    if (tid == 0) { sh_B = B; sh_B1k = B1k; sh_cA = 0; sh_cE = 0; sh_cT = 0; }
  }
  __syncthreads();
  u32 B = sh_B, B1k = sh_B1k;
  bool doT = (B1k > B);
  if (tid == 0 && q == 0) { B_g[lane] = B; B1k_g[lane] = B1k; }
  const float4* S4 = (const float4*)(scores_t + (size_t)lane * A_PAD + q * QCH);
  int base_idx = q * QCH;
  for (int i = tid; i < QCH / 4; i += 512) {
    float4 v = S4[i];
    u32 ks[4] = {__float_as_uint(v.x), __float_as_uint(v.y), __float_as_uint(v.z), __float_as_uint(v.w)};
    #pragma unroll
    for (int j = 0; j < 4; ++j) {
      u32 k = ks[j], bkt = k >> 19;
      u32 idx = (u32)(base_idx + i * 4 + j);
      if (bkt > B) {
        u32 p = atomicAdd(&sh_cA, 1u);
        if (p < 5120u) bufA[p] = pack_key(k, idx);
        if (doT && bkt >= B1k) {
          u32 pt = atomicAdd(&sh_cT, 1u);
          if (pt < 2048u) bufT[pt] = pack_key(k, idx);
        }
      } else if (bkt == B) {
        u32 p = atomicAdd(&sh_cE, 1u);
        if (p < 2048u) bufE[p] = pack_key(k, idx);
      }
    }
  }
  __syncthreads();
  u32 cA = sh_cA; if (cA > 5120u) cA = 5120u;
  u32 cE = sh_cE; if (cE > 2048u) cE = 2048u;
  u32 cT = sh_cT; if (cT > 2048u) cT = 2048u;
  if (tid == 0) {
    sh_baseA = atomicAdd(&cntA_g[lane], sh_cA);
    sh_baseE = atomicAdd(&cntE_g[lane], sh_cE);
    sh_baseT = atomicAdd(&cntT_g[lane], sh_cT);
  }
  __syncthreads();
  u32 bA = sh_baseA, bE = sh_baseE, bT = sh_baseT;
  u64* LA = listA_g + (size_t)lane * 5120;
  u64* LE = listE_g + (size_t)lane * 2048;
  u64* LT = listT_g + (size_t)lane * 2048;
  for (u32 i = tid; i < cA; i += 512) { u32 d = bA + i; if (d < 5120u) LA[d] = bufA[i]; }
  for (u32 i = tid; i < cE; i += 512) { u32 d = bE + i; if (d < 2048u) LE[d] = bufE[i]; }
  for (u32 i = tid; i < cT; i += 512) { u32 d = bT + i; if (d < 2048u) LT[d] = bufT[i]; }
}

// ---------------- per-lane NMS: fast sorted-top-T path + exact fallback ----------------
__global__ __launch_bounds__(NTH) void nms_kernel(
    const float* __restrict__ scores_t, const float* __restrict__ boxes,
    u64* __restrict__ listA_g, u64* __restrict__ listE_g, const u64* __restrict__ listT_g,
    const u32* __restrict__ cntA_g, const u32* __restrict__ cntE_g, const u32* __restrict__ cntT_g,
    const u32* __restrict__ B_g, const u32* __restrict__ B1k_g,
    float* __restrict__ nms_s, float* __restrict__ nms_b)
{
  __shared__ u64 key_s[2048];                   // 16 KB sorted chunk keys (u32[4096] scratch in fallback)
  __shared__ __align__(16) float4 box_s[2048];  // 32 KB chunk boxes; u64/u32 scratch during build
  __shared__ u64 ebuf[2048];                    // 16 KB: histL u32[4096] / listE
  __shared__ float4 wbox[MAXT];
  __shared__ u32 wtot[4];
  __shared__ u64 sh_minPrev;
  __shared__ u32 sh_w, sh_done, sh_eidx, sh_Rthr, sh_eSorted, sh_big, sh_C;
  __shared__ u32 sh_B, sh_incl, sh_above, sh_total;
  __shared__ u32 sh_c0, sh_c1, sh_B2;

  u32* histL  = (u32*)ebuf;
  u32* cntArr = (u32*)box_s;

  int tid = threadIdx.x;
  int lane = blockIdx.x;
  int b = lane / NCLS;
  const float4* boxes4 = (const float4*)boxes;
  size_t bbase = (size_t)b * A_TOTAL;
  const u64 thrpack = ((u64)KTHR) << 32;

  u32 g = cntA_g[lane];
  u32 h = cntE_g[lane];
  u32 B = B_g[lane];
  u32 B1k = B1k_g[lane];
  u32 cT = cntT_g[lane];
  u64* LAm = listA_g + (size_t)lane * 5120;
  u64* LEg = listE_g + (size_t)lane * 2048;

  if (tid == 0) {
    sh_w = 0; sh_done = 0; sh_eidx = 0; sh_eSorted = 0; sh_minPrev = ~0ull;
  }
  __syncthreads();

  const float LO0  = 0.04f;
  const float INV0 = 4096.0f / (1.001f - 0.04f);

  float* outS = nms_s + (size_t)lane * MAXT;
  float* outB = nms_b + (size_t)lane * MAXT * 4;

  // ================= FAST PATH: counting-sort listT, lazy scan =================
  bool fastOK = (B1k > B) && (cT > 0) && (cT <= 2048u) && (h <= 2048u);
  if (fastOK) {
    u64* raw = (u64*)box_s;
    const u64* LT = listT_g + (size_t)lane * 2048;
    for (u32 i = tid; i < cT; i += NTH) raw[i] = LT[i];
    for (int i = tid; i < 4096; i += NTH) histL[i] = 0;
    __syncthreads();
    for (u32 i = tid; i < cT; i += NTH) {
      u64 k = raw[i];
      if (k >= thrpack) {
        float s = __uint_as_float((u32)(k >> 32));
        int d = (int)((s - LO0) * INV0); d = min(max(d, 0), 4095);
        atomicAdd(&histL[d], 1u);
      }
    }
    __syncthreads();
    // descending exclusive prefix; also capture total C
    {
      int t0 = tid << 4;
      u32 hloc[16]; u32 ssum = 0;
      #pragma unroll
      for (int j = 0; j < 16; ++j) { hloc[j] = histL[t0 + j]; ssum += hloc[j]; }
      int wl = tid & 63, wid = tid >> 6;
      u32 suf = ssum;
      #pragma unroll
      for (int off = 1; off < 64; off <<= 1) {
        u32 v = __shfl_down(suf, off, 64);
        if (wl < 64 - off) suf += v;
      }
      if (wl == 0) wtot[wid] = suf;
      __syncthreads();
      if (tid == 0) sh_C = wtot[0] + wtot[1] + wtot[2] + wtot[3];
      u32 cross = 0;
      for (int w2 = wid + 1; w2 < 4; ++w2) cross += wtot[w2];
      u32 run = (suf - ssum) + cross;
      #pragma unroll
      for (int j = 15; j >= 0; --j) { u32 b2 = run; run += hloc[j]; histL[t0 + j] = b2; }
    }
    __syncthreads();
    u32 C = sh_C;
    if (C > 0) {
      // scatter: atomicAdd on the base array itself; after scatter histL[d] = end[d]
      for (u32 i = tid; i < cT; i += NTH) {
        u64 k = raw[i];
        if (k >= thrpack) {
          float s = __uint_as_float((u32)(k >> 32));
          int d = (int)((s - LO0) * INV0); d = min(max(d, 0), 4095);
          u32 pos = atomicAdd(&histL[d], 1u);
          if (pos < 2048u) key_s[pos] = k;
        }
      }
      __syncthreads();
      // per-bucket insertion minisort; bucket d occupies [histL[d+1], histL[d]) (desc bases)
      {
        int t0 = tid << 4;
        for (int j = 0; j < 16; ++j) {
          u32 d = (u32)(t0 + j);
          u32 end = histL[d];
          u32 start = (d == 4095u) ? 0u : histL[d + 1];
          if (end > start + 1u) {
            for (u32 a2 = start + 1; a2 < end; ++a2) {
              u64 kv = key_s[a2];
              int bi = (int)a2 - 1;
              while (bi >= (int)start && key_s[bi] < kv) { key_s[bi + 1] = key_s[bi]; --bi; }
              key_s[bi + 1] = kv;
            }
          }
        }
      }
      __syncthreads();
      if (tid == 0) sh_minPrev = key_s[C - 1];
      for (u32 p = tid; p < C; p += NTH) {
        u32 idx = 0xFFFFFFFFu - (u32)(key_s[p] & 0xFFFFFFFFull);
        box_s[p] = boxes4[bbase + idx];
      }
      __syncthreads();
      if (tid < 64) {
        int w = lazy_scan(key_s, box_s, C, wbox, outS, outB, 0, tid);
        if (tid == 0) sh_w = (u32)w;
      }
    }
  }
  __syncthreads();

  // ================= FALLBACK: full exact machinery (rare) =================
  if (sh_w < MAXT) {
    // rare: global listE overflowed -> refine boundary on bits [18:7], spill listE
    if (h > 2048u) {
      const float* S = scores_t + (size_t)lane * A_PAD;
      for (int i = tid; i < 4096; i += NTH) histL[i] = 0;
      if (tid == 0) { sh_c0 = 0; sh_c1 = 0; }
      __syncthreads();
      for (int i = tid; i < A_PAD; i += NTH) {
        u32 k = __float_as_uint(S[i]);
        if ((k >> 19) == B) atomicAdd(&histL[(k >> 7) & 0xFFFu], 1u);
      }
      __syncthreads();
      u32 R1 = KTOP - g;
      if (tid < 64) {
        u32 Bx, ix, ax, tx;
        cut4096w(histL, R1, tid, Bx, ix, ax, tx);
        if (tid == 0) sh_B2 = Bx;
      }
      __syncthreads();
      u32 B2 = sh_B2;
      __syncthreads();
      for (int i = tid; i < A_PAD; i += NTH) {
        u32 k = __float_as_uint(S[i]);
        if ((k >> 19) == B) {
          u32 sb = (k >> 7) & 0xFFFu;
          if (sb > B2) {
            u32 p = atomicAdd(&sh_c0, 1u);
            if (g + p < 5120u) LAm[g + p] = pack_key(k, (u32)i);
          } else if (sb == B2) {
            u32 p = atomicAdd(&sh_c1, 1u);
            if (p < 2048u) ebuf[p] = pack_key(k, (u32)i);
          }
        }
      }
      __syncthreads();
      g += sh_c0; if (g > 5120u) g = 5120u;
      h = sh_c1;  if (h > 2048u) h = 2048u;
      for (u32 i = tid; i < h; i += NTH) LEg[i] = ebuf[i];
      __syncthreads();
    }
    g = (g > 5120u) ? 5120u : g;
    u32 R = (g < KTOP) ? (KTOP - g) : 0u;
    if (R > h) R = h;

    // listA keys -> registers (threshold-filtered; 0 = empty)
    u64 ak[20];
    #pragma unroll
    for (int r = 0; r < 20; ++r) {
      u32 s = (u32)tid + (u32)r * NTH;
      u64 kp = (s < g) ? LAm[s] : 0ull;
      if (kp < thrpack) kp = 0ull;
      ak[r] = kp;
    }

    // ================= segment loop =================
    for (int seg = 0; seg < 7200; ++seg) {
      __syncthreads();
      if (sh_w >= MAXT || sh_done) break;
      u64 minPrev = sh_minPrev;

      int digLvl = 0;
      u32 A_B0 = 0, A_B1 = 0;
      float lo1 = 0.f, inv1 = 0.f;
      u64 kMask = 0, kPref = 0;
      int m1shift = 32;
      int selMode = -1;
      u32 selB = 0;
      u32 C = 0;
      bool fromE = false;

      for (int lvl = 0; lvl < 8; ++lvl) {
        for (int i = tid; i < 4096; i += NTH) histL[i] = 0;
        __syncthreads();
        #pragma unroll
        for (int r = 0; r < 20; ++r) {
          u64 k = ak[r];
          if (!k || k >= minPrev) continue;
          float s = __uint_as_float((u32)(k >> 32));
          if (digLvl >= 1) { int d0 = (int)((s - LO0) * INV0); d0 = min(max(d0, 0), 4095); if ((u32)d0 != A_B0) continue; }
          if (digLvl >= 2) { int d1 = (int)((s - lo1) * inv1); d1 = min(max(d1, 0), 4095); if ((u32)d1 != A_B1) continue; }
          if (digLvl >= 3 && ((k & kMask) != kPref)) continue;
          u32 d;
          if (digLvl == 0)      { int t0 = (int)((s - LO0) * INV0); d = (u32)min(max(t0, 0), 4095); }
          else if (digLvl == 1) { int t1 = (int)((s - lo1) * inv1); d = (u32)min(max(t1, 0), 4095); }
          else                  d = (u32)((k >> m1shift) & 0xFFFull);
          atomicAdd(&histL[d], 1u);
        }
        __syncthreads();
        if (tid < 64) {
          u32 Bx, ix, ax, tx;
          cut4096w(histL, 1024u, tid, Bx, ix, ax, tx);
          if (tid == 0) { sh_B = Bx; sh_incl = ix; sh_above = ax; sh_total = tx; }
        }
        __syncthreads();
        u32 total = sh_total, incl = sh_incl, above = sh_above, Bx = sh_B;
        if (total == 0u)   { fromE = true; break; }
        if (total < 1024u) { selMode = 0; C = total; break; }
        if (incl <= 2048u) { selMode = 1; selB = Bx; C = incl; break; }
        if (above > 0u)    { selMode = 2; selB = Bx; C = above; break; }
        if (digLvl == 0) {
          A_B0 = Bx;
          lo1 = LO0 + (float)Bx / INV0;
          inv1 = INV0 * 4096.0f;
          digLvl = 1;
        } else if (digLvl == 1) {
          A_B1 = Bx;
          digLvl = 2; m1shift = 32;
        } else {
          kPref |= ((u64)Bx << m1shift);
          kMask |= (0xFFFull << m1shift);
          m1shift -= 12;
          digLvl++;
        }
        __syncthreads();
      }

      if (fromE) {
        if (!sh_eSorted) {
          for (u32 i = tid; i < h; i += NTH) ebuf[i] = LEg[i];
          __syncthreads();
          bitonic_desc(ebuf, h, tid, NTH);
          for (u32 i = tid; i < h; i += NTH) LEg[i] = ebuf[i];
          if (tid == 0) {
            u32 lo = 0, hi2 = h;
            while (lo < hi2) { u32 mid = (lo + hi2) >> 1; if (ebuf[mid] >= thrpack) lo = mid + 1; else hi2 = mid; }
            sh_Rthr = (R < lo) ? R : lo;
            sh_eSorted = 1;
          }
          __syncthreads();
        }
        u32 eidx = sh_eidx;
        u32 take = (sh_Rthr > eidx) ? (sh_Rthr - eidx) : 0u;
        if (take > 2048u) take = 2048u;
        if (take == 0u) { if (tid == 0) sh_done = 1; continue; }
        for (u32 i = tid; i < take; i += NTH) key_s[i] = LEg[eidx + i];
        C = take;
        if (tid == 0) sh_eidx = eidx + take;
      } else {
        u32 hloc[16];
        {
          int t0 = tid << 4;
          u32 ssum = 0;
          #pragma unroll
          for (int j = 0; j < 16; ++j) { hloc[j] = histL[t0 + j]; ssum += hloc[j]; }
          int wl = tid & 63, wid = tid >> 6;
          u32 suf = ssum;
          #pragma unroll
          for (int off = 1; off < 64; off <<= 1) {
            u32 v = __shfl_down(suf, off, 64);
            if (wl < 64 - off) suf += v;
          }
          if (wl == 0) wtot[wid] = suf;
          __syncthreads();
          u32 cross = 0;
          for (int w2 = wid + 1; w2 < 4; ++w2) cross += wtot[w2];
          u32 run = (suf - ssum) + cross;
          #pragma unroll
          for (int j = 15; j >= 0; --j) { u32 base2 = run; run += hloc[j]; histL[t0 + j] = base2; }
        }
        for (int i = tid; i < 4096; i += NTH) cntArr[i] = 0;
        if (tid == 0) sh_big = 0;
        __syncthreads();
        #pragma unroll
        for (int r = 0; r < 20; ++r) {
          u64 k = ak[r];
          if (!k || k >= minPrev) continue;
          float s = __uint_as_float((u32)(k >> 32));
          if (digLvl >= 1) { int d0 = (int)((s - LO0) * INV0); d0 = min(max(d0, 0), 4095); if ((u32)d0 != A_B0) continue; }
          if (digLvl >= 2) { int d1 = (int)((s - lo1) * inv1); d1 = min(max(d1, 0), 4095); if ((u32)d1 != A_B1) continue; }
          if (digLvl >= 3 && ((k & kMask) != kPref)) continue;
          u32 d;
          if (digLvl == 0)      { int t0x = (int)((s - LO0) * INV0); d = (u32)min(max(t0x, 0), 4095); }
          else if (digLvl == 1) { int t1x = (int)((s - lo1) * inv1); d = (u32)min(max(t1x, 0), 4095); }
          else                  d = (u32)((k >> m1shift) & 0xFFFull);
          if (selMode == 1)      { if (d < selB) continue; }
          else if (selMode == 2) { if (d <= selB) continue; }
          u32 pos = histL[d] + atomicAdd(&cntArr[d], 1u);
          if (pos < 2048u) key_s[pos] = k;
        }
        __syncthreads();
        {
          int t0 = tid << 4;
          for (int j = 0; j < 16; ++j) {
            u32 bkt = (u32)(t0 + j);
            u32 c = cntArr[bkt];
            if (c >= 2u) {
              if (c <= 48u) {
                u32 basep = histL[bkt];
                for (u32 a2 = 1; a2 < c; ++a2) {
                  u64 kv = key_s[basep + a2];
                  int bi = (int)a2 - 1;
                  while (bi >= 0 && key_s[basep + bi] < kv) { key_s[basep + bi + 1] = key_s[basep + bi]; --bi; }
                  key_s[basep + bi + 1] = kv;
                }
              } else sh_big = 1;
            }
          }
        }
        __syncthreads();
        if (sh_big) bitonic_desc(key_s, C, tid, NTH);
        if (tid == 0) sh_minPrev = key_s[C - 1];
      }
      __syncthreads();

      for (u32 p = tid; p < C; p += NTH) {
        u32 idx = 0xFFFFFFFFu - (u32)(key_s[p] & 0xFFFFFFFFull);
        box_s[p] = boxes4[bbase + idx];
      }
      __syncthreads();

      if (tid < 64) {
        int w = lazy_scan(key_s, box_s, C, wbox, outS, outB, (int)sh_w, tid);
        if (tid == 0) sh_w = (u32)w;
      }
    }
  }

  // ---- padding like reference ----
  __syncthreads();
  u32 w = sh_w;
  for (u32 p = w + (u32)tid; p < MAXT; p += NTH) {
    outS[p] = -1.0f;
    *(float4*)(outB + p * 4) = make_float4(0.f, 0.f, 0.f, 0.f);
  }
}

// ---------------- final per-batch top-100: radix rank-select ----------------
__global__ __launch_bounds__(256) void merge_kernel(
    const float* __restrict__ nms_s, const float* __restrict__ nms_b,
    float* __restrict__ out_b, float* __restrict__ out_s,
    float* __restrict__ out_c, float* __restrict__ out_v)
{
  __shared__ u64 keys[NCLS * MAXT];   // 72 KB
  __shared__ u32 hist[4096];          // 16 KB
  __shared__ u64 sel[640];
  __shared__ u32 sh_cnt, sh_valid;
  __shared__ u32 sh_B, sh_incl, sh_above, sh_total;

  int b = blockIdx.x, tid = threadIdx.x;
  const int NTOT = NCLS * MAXT;

  for (int i = tid; i < NTOT; i += 256) {
    float s = nms_s[(size_t)b * NTOT + i];
    u32 u = __float_as_uint(s);
    u = (u & 0x80000000u) ? ~u : (u | 0x80000000u);
    keys[i] = ((u64)u << 32) | (u64)(0xFFFFFFFFu - (u32)i);
  }
  if (tid == 0) { sh_cnt = 0; sh_valid = 0; }

  u64 prefVal = 0;
  u64 T = 0;
  u32 need = MAXT;
  const int shifts[6] = {52, 40, 28, 16, 4, 0};
  const int widths[6] = {12, 12, 12, 12, 12, 4};
  for (int lvl = 0; lvl < 6; ++lvl) {
    int s = shifts[lvl], w = widths[lvl];
    for (int i = tid; i < 4096; i += 256) hist[i] = 0;
    __syncthreads();
    u32 dmask = (1u << w) - 1u;
    for (int i = tid; i < NTOT; i += 256) {
      u64 k = keys[i];
      if (lvl > 0 && (k >> (s + w)) != (prefVal >> (s + w))) continue;
      atomicAdd(&hist[(u32)((k >> s) & dmask)], 1u);
    }
    __syncthreads();
    if (tid < 64) {
      u32 Bx, ix, ax, tx;
      cut4096w(hist, need, tid, Bx, ix, ax, tx);
      if (tid == 0) { sh_B = Bx; sh_incl = ix; sh_above = ax; sh_total = tx; }
    }
    __syncthreads();
    u32 B = sh_B, incl = sh_incl, above = sh_above;
    if (incl <= 512u || lvl == 5) {
      T = prefVal | ((u64)B << s);
      break;
    }
    prefVal |= ((u64)B << s);
    need -= above;
  }
  __syncthreads();

  for (int i = tid; i < NTOT; i += 256) {
    u64 k = keys[i];
    if (k >= T) {
      u32 p = atomicAdd(&sh_cnt, 1u);
      if (p < 640u) sel[p] = k;
    }
  }
  __syncthreads();
  u32 cnt = sh_cnt; if (cnt > 640u) cnt = 640u;

  for (u32 j = tid; j < cnt; j += 256) {
    u64 kj = sel[j];
    u32 r = 0;
    for (u32 i = 0; i < cnt; ++i) r += (sel[i] > kj) ? 1u : 0u;
    if (r < (u32)MAXT) {
      u32 u = (u32)(kj >> 32);
      u32 bits = (u & 0x80000000u) ? (u ^ 0x80000000u) : ~u;
      float sc = __uint_as_float(bits);
      u32 flat = 0xFFFFFFFFu - (u32)(kj & 0xFFFFFFFFull);
      int cls = (int)(flat / MAXT), pos = (int)(flat % MAXT);
      out_s[b * MAXT + r] = sc;
      out_c[b * MAXT + r] = (float)(cls + 1);
      *(float4*)(out_b + ((size_t)b * MAXT + r) * 4) =
          *(const float4*)(nms_b + (((size_t)b * NCLS + cls) * MAXT + pos) * 4);
      if (sc > -1.0f) atomicAdd(&sh_valid, 1u);
    }
  }
  __syncthreads();
  if (tid == 0) out_v[b] = (float)sh_valid;
}

extern "C" void kernel_launch(void* const* d_in, const int* in_sizes, int n_in,
                              void* d_out, int out_size, void* d_ws, size_t ws_size,
                              hipStream_t stream)
{
  const float* box[5]; const float* cls[5]; const float* anc[5];
  bool interleaved = (in_sizes[1] == 2 * 57600 * 91);   // setup_inputs dict order
  if (interleaved) {
    for (int l = 0; l < 5; ++l) {
      box[l] = (const float*)d_in[3 * l + 0];
      cls[l] = (const float*)d_in[3 * l + 1];
      anc[l] = (const float*)d_in[3 * l + 2];
    }
  } else {
    for (int l = 0; l < 5; ++l) {
      box[l] = (const float*)d_in[l];
      cls[l] = (const float*)d_in[5 + l];
      anc[l] = (const float*)d_in[10 + l];
    }
  }
  const float* img = (const float*)d_in[15];

  float* ws = (float*)d_ws;
  float* boxes_ws = ws;                          // 613800 f
  float* scores_t = boxes_ws + 613800;           // 180*76736       = 13812480 f
  u32*   hist_g   = (u32*)(scores_t + 13812480); // 180*4096        = 737280 u32
  u32*   cntA_g   = hist_g + 737280;             // 180
  u32*   cntE_g   = cntA_g + 180;                // 180
  u32*   B_g      = cntE_g + 180;                // 180
  u32*   B1k_g    = B_g + 180;                   // 180
  u32*   cntT_g   = B1k_g + 180;                 // 180
  u64*   listA_g  = (u64*)(cntT_g + 180);        // 180*5120 u64
  u64*   listE_g  = listA_g + 180 * 5120;        // 180*2048 u64
  u64*   listT_g  = listE_g + 180 * 2048;        // 180*2048 u64
  float* nms_s    = (float*)(listT_g + 180 * 2048);  // 18000 f
  float* nms_b    = nms_s + 18000;               // 72000 f

  decode_kernel<<<600, 256, 0, stream>>>(
      box[0], box[1], box[2], box[3], box[4],
      anc[0], anc[1], anc[2], anc[3], anc[4], img, boxes_ws, hist_g, scores_t);

  transpose_kernel<<<2402, 256, 0, stream>>>(cls[0], cls[1], cls[2], cls[3], cls[4], scores_t);

  hist_kernel<<<720, 512, 0, stream>>>(scores_t, hist_g);

  collect_kernel<<<720, 512, 0, stream>>>(scores_t, hist_g, listA_g, listE_g, listT_g,
                                          cntA_g, cntE_g, cntT_g, B_g, B1k_g);

  nms_kernel<<<180, NTH, 0, stream>>>(scores_t, boxes_ws, listA_g, listE_g, listT_g,
                                      cntA_g, cntE_g, cntT_g, B_g, B1k_g, nms_s, nms_b);

  float* out_b = (float*)d_out;  // [2][100][4]
  float* out_s = out_b + 800;    // [2][100]
  float* out_c = out_s + 200;    // [2][100]
  float* out_v = out_c + 200;    // [2]
  merge_kernel<<<2, 256, 0, stream>>>(nms_s, nms_b, out_b, out_s, out_c, out_v);
}